// Round 2
// 3117.018 us; speedup vs baseline: 3.0470x; 3.0470x over previous
//
#include <hip/hip_runtime.h>
#include <math.h>

// ---------------- problem constants ----------------
constexpr int L_ = 4, E_ = 512, Hn_ = 8, X_ = 8, Kk_ = 2, V_ = 32000;
constexpr int B_ = 8, T_ = 1024, HIGH_ = 32000, HID_ = 1024;
constexpr int Dh_ = E_ / Hn_;      // 64
constexpr int HALF_ = Dh_ / 2;     // 32
constexpr int NTOK = B_ * T_;      // 8192
constexpr int CAP_ = NTOK * Kk_ / X_; // 2048
constexpr int FF_ = 4 * E_;        // 2048

typedef short short8 __attribute__((ext_vector_type(8)));
typedef float f32x4 __attribute__((ext_vector_type(4)));

__device__ __forceinline__ float wave_sum(float v) {
#pragma unroll
  for (int off = 32; off; off >>= 1) v += __shfl_xor(v, off, 64);
  return v;
}
__device__ __forceinline__ float wave_max(float v) {
#pragma unroll
  for (int off = 32; off; off >>= 1) v = fmaxf(v, __shfl_xor(v, off, 64));
  return v;
}

__device__ __forceinline__ unsigned short f2bf(float x) {
  union { float f; unsigned u; } v; v.f = x;
  unsigned r = v.u + 0x7FFFu + ((v.u >> 16) & 1u);   // RNE
  return (unsigned short)(r >> 16);
}
__device__ __forceinline__ float bf2f(unsigned short h) {
  union { unsigned u; float f; } v; v.u = ((unsigned)h) << 16;
  return v.f;
}

// ---------------- split cast: fp32 -> (hi bf16, lo bf16) planes ----------------
__global__ __launch_bounds__(256)
void split_cast_kernel(const float* __restrict__ src, unsigned short* __restrict__ hi,
                       unsigned short* __restrict__ lo, int n) {
  int i = (blockIdx.x * 256 + threadIdx.x) * 4;
  if (i >= n) return;
  float4 v = *(const float4*)(src + i);
  float vv[4] = {v.x, v.y, v.z, v.w};
#pragma unroll
  for (int j = 0; j < 4; ++j) {
    unsigned short h = f2bf(vv[j]);
    hi[i + j] = h;
    lo[i + j] = f2bf(vv[j] - bf2f(h));
  }
}

// ---------------- embedding ----------------
__global__ __launch_bounds__(256)
void embed_kernel(const float* __restrict__ tok_emb, const float* __restrict__ pos_emb,
                  const int* __restrict__ ids, float* __restrict__ x) {
  int tok = blockIdx.x;
  int t = tok & (T_ - 1);
  int id = ids[tok];
  const float* te = tok_emb + (size_t)id * E_;
  const float* pe = pos_emb + (size_t)t * E_;
  float* xr = x + (size_t)tok * E_;
  int tid = threadIdx.x;
  xr[tid]       = te[tid]       + pe[tid];
  xr[tid + 256] = te[tid + 256] + pe[tid + 256];
}

// ---------------- layernorm ----------------
__global__ __launch_bounds__(256)
void ln_kernel(const float* __restrict__ x, const float* __restrict__ w,
               const float* __restrict__ b, float* __restrict__ o) {
  int row = blockIdx.x, tid = threadIdx.x;
  const float* xr = x + (size_t)row * E_;
  float a0 = xr[tid], a1 = xr[tid + 256];
  __shared__ float red[4];
  float s = wave_sum(a0 + a1);
  if ((tid & 63) == 0) red[tid >> 6] = s;
  __syncthreads();
  float mean = (red[0] + red[1] + red[2] + red[3]) * (1.f / E_);
  float d0 = a0 - mean, d1 = a1 - mean;
  __syncthreads();
  float sq = wave_sum(d0 * d0 + d1 * d1);
  if ((tid & 63) == 0) red[tid >> 6] = sq;
  __syncthreads();
  float var = (red[0] + red[1] + red[2] + red[3]) * (1.f / E_);
  float rstd = 1.f / sqrtf(var + 1e-5f);
  float* orow = o + (size_t)row * E_;
  orow[tid]       = d0 * rstd * w[tid]       + b[tid];
  orow[tid + 256] = d1 * rstd * w[tid + 256] + b[tid + 256];
}

// ======================= split-bf16 MFMA GEMM =======================
// C[M][N] = A[M][K] @ W[N][K]^T  with A,W given as hi/lo bf16 planes.
// acc += aH*bH + aH*bL + aL*bH  (~fp32 precision, 3x MFMA).
// Block 256 = 4 waves (2x2), tile 128x128, BK=32.
// MODE 0: C = acc (plain store)            [qkv]
// MODE 1: C += acc (accumulate)            [att-out residual]
// MODE 2: gather A rows via elist; out = relu(acc+bias) split-stored to Oh/Ol [expert up]
// MODE 3: scatter: x[rows[m]] += (acc+bias[n])*gate[m] atomically           [expert down]
template <int MODE>
__global__ __launch_bounds__(256)
void mfma_gemm(const unsigned short* __restrict__ Ah, const unsigned short* __restrict__ Al,
               int lda,
               const unsigned short* __restrict__ Wh, const unsigned short* __restrict__ Wl,
               const float* __restrict__ bias, float* __restrict__ C,
               unsigned short* __restrict__ Oh, unsigned short* __restrict__ Ol,
               const int* __restrict__ elist, const float* __restrict__ egates, int e0,
               int M, int N, int K) {
  int z = blockIdx.z;
  const int* rows = nullptr;
  const float* gates = nullptr;
  if (MODE == 2) {
    Wh += (size_t)z * N * K;  Wl += (size_t)z * N * K;
    bias += (size_t)(e0 + z) * N;
    rows = elist + (size_t)(e0 + z) * CAP_;
    Oh += (size_t)z * M * N;  Ol += (size_t)z * M * N;
  }
  if (MODE == 3) {
    Ah += (size_t)z * M * K;  Al += (size_t)z * M * K;
    Wh += (size_t)z * N * K;  Wl += (size_t)z * N * K;
    bias += (size_t)(e0 + z) * N;
    rows = elist + (size_t)(e0 + z) * CAP_;
    gates = egates + (size_t)(e0 + z) * CAP_;
  }

  __shared__ __align__(16) unsigned short Ah_s[128][40];
  __shared__ __align__(16) unsigned short Al_s[128][40];
  __shared__ __align__(16) unsigned short Bh_s[128][40];
  __shared__ __align__(16) unsigned short Bl_s[128][40];

  int tid = threadIdx.x;
  int m0 = blockIdx.y * 128, n0 = blockIdx.x * 128;
  int w = tid >> 6, lane = tid & 63;
  int wm = w >> 1, wn = w & 1;
  int lm = lane & 15, q8 = (lane >> 4) * 8, q4 = (lane >> 4) * 4;

  // staging assignment: thread -> (row r, k-half seg)
  int r = tid >> 1, seg = tid & 1;
  size_t arow = (MODE == 2) ? (size_t)rows[m0 + r] : (size_t)(m0 + r);
  const unsigned short* pAh = Ah + arow * (size_t)lda + seg * 16;
  const unsigned short* pAl = Al + arow * (size_t)lda + seg * 16;
  const unsigned short* pWh = Wh + (size_t)(n0 + r) * K + seg * 16;
  const unsigned short* pWl = Wl + (size_t)(n0 + r) * K + seg * 16;

  f32x4 acc[4][4];
#pragma unroll
  for (int i = 0; i < 4; ++i)
#pragma unroll
    for (int j = 0; j < 4; ++j) acc[i][j] = {0.f, 0.f, 0.f, 0.f};

  for (int k0 = 0; k0 < K; k0 += 32) {
    uint4 a0 = *(const uint4*)(pAh + k0);
    uint4 a1 = *(const uint4*)(pAh + k0 + 8);
    uint4 l0 = *(const uint4*)(pAl + k0);
    uint4 l1 = *(const uint4*)(pAl + k0 + 8);
    uint4 b0 = *(const uint4*)(pWh + k0);
    uint4 b1 = *(const uint4*)(pWh + k0 + 8);
    uint4 c0 = *(const uint4*)(pWl + k0);
    uint4 c1 = *(const uint4*)(pWl + k0 + 8);
    *(uint4*)&Ah_s[r][seg * 16]     = a0;
    *(uint4*)&Ah_s[r][seg * 16 + 8] = a1;
    *(uint4*)&Al_s[r][seg * 16]     = l0;
    *(uint4*)&Al_s[r][seg * 16 + 8] = l1;
    *(uint4*)&Bh_s[r][seg * 16]     = b0;
    *(uint4*)&Bh_s[r][seg * 16 + 8] = b1;
    *(uint4*)&Bl_s[r][seg * 16]     = c0;
    *(uint4*)&Bl_s[r][seg * 16 + 8] = c1;
    __syncthreads();

    short8 aH[4], aL[4], bH[4], bL[4];
#pragma unroll
    for (int i = 0; i < 4; ++i) {
      aH[i] = *(const short8*)&Ah_s[wm * 64 + i * 16 + lm][q8];
      aL[i] = *(const short8*)&Al_s[wm * 64 + i * 16 + lm][q8];
    }
#pragma unroll
    for (int j = 0; j < 4; ++j) {
      bH[j] = *(const short8*)&Bh_s[wn * 64 + j * 16 + lm][q8];
      bL[j] = *(const short8*)&Bl_s[wn * 64 + j * 16 + lm][q8];
    }
#pragma unroll
    for (int i = 0; i < 4; ++i)
#pragma unroll
      for (int j = 0; j < 4; ++j) {
        acc[i][j] = __builtin_amdgcn_mfma_f32_16x16x32_bf16(aH[i], bH[j], acc[i][j], 0, 0, 0);
        acc[i][j] = __builtin_amdgcn_mfma_f32_16x16x32_bf16(aH[i], bL[j], acc[i][j], 0, 0, 0);
        acc[i][j] = __builtin_amdgcn_mfma_f32_16x16x32_bf16(aL[i], bH[j], acc[i][j], 0, 0, 0);
      }
    __syncthreads();
  }

  // epilogue: D element (i,j,reg): m = m0+wm*64+i*16+q4+reg, n = n0+wn*64+j*16+lm
#pragma unroll
  for (int i = 0; i < 4; ++i) {
#pragma unroll
    for (int rg = 0; rg < 4; ++rg) {
      int m = m0 + wm * 64 + i * 16 + q4 + rg;
      int tokr = 0; float g = 0.f;
      if (MODE == 3) { tokr = rows[m]; g = gates[m]; }
#pragma unroll
      for (int j = 0; j < 4; ++j) {
        int n = n0 + wn * 64 + j * 16 + lm;
        float v = acc[i][j][rg];
        if (MODE == 0) {
          C[(size_t)m * N + n] = v;
        } else if (MODE == 1) {
          C[(size_t)m * N + n] += v;
        } else if (MODE == 2) {
          v = fmaxf(v + bias[n], 0.f);
          unsigned short hv16 = f2bf(v);
          Oh[(size_t)m * N + n] = hv16;
          Ol[(size_t)m * N + n] = f2bf(v - bf2f(hv16));
        } else {  // MODE 3
          if (g != 0.f)
            atomicAdd(&C[(size_t)tokr * N + n], (v + bias[n]) * g);
        }
      }
    }
  }
}

// ---------------- RoPE in-place on q,k inside qkv ----------------
__global__ __launch_bounds__(256)
void rope_kernel(float* __restrict__ qkv) {
  int tok = blockIdx.x;
  int t = tok & (T_ - 1);
  int hh = threadIdx.x >> 5, j = threadIdx.x & 31;
  float inv = __expf((float)j * (-logf(10000.f) / 32.f));
  float ang = (float)t * inv;
  float sn = sinf(ang), cs = cosf(ang);
  float* qp = qkv + (size_t)tok * 3 * E_ + hh * Dh_;
  float* kp = qp + E_;
  float q1 = qp[j], q2 = qp[j + HALF_];
  qp[j] = q1 * cs - q2 * sn;
  qp[j + HALF_] = q2 * cs + q1 * sn;
  float k1 = kp[j], k2 = kp[j + HALF_];
  kp[j] = k1 * cs - k2 * sn;
  kp[j + HALF_] = k2 * cs + k1 * sn;
}

// ---------------- MFMA flash attention ----------------
// Swapped-operand scheme: S^T[key][q] = mfma(A=K, B=Q) needs NO transposes (both
// [row][d], contraction on d). Softmax stats live per-lane (q = lane&15).
// PV: O^T[d][q] = mfma(A=V^T, B=P); V transposed during LDS staging, P goes
// accumulator -> LDS (packed b64) -> B-fragments. Split-bf16 hi/lo planes with
// 3-MFMA products (~fp32 precision, same scheme as the verified GEMMs).
// Block = 256 thr = 4 waves; wave w owns q rows qt0 + w*16 .. +15; KV tile = 64.
// LDS rows padded to 72 shorts (144 B): 16B-aligned b128 ops, bank-rotation makes
// the fragment ds_read_b128s conflict-free (8 lanes per 16B class = wave64 min).
__global__ __launch_bounds__(256)
void attn_mfma_kernel(const float* __restrict__ qkv, float* __restrict__ att) {
  __shared__ __align__(16) unsigned short Kh_s[64][72];
  __shared__ __align__(16) unsigned short Kl_s[64][72];
  __shared__ __align__(16) unsigned short Vth_s[64][72];
  __shared__ __align__(16) unsigned short Vtl_s[64][72];
  __shared__ __align__(16) unsigned short Ph_s[4][16][72];
  __shared__ __align__(16) unsigned short Pl_s[4][16][72];

  const int b = blockIdx.y >> 3, hh = blockIdx.y & 7;
  const int qt0 = blockIdx.x * 64;
  const int tid = threadIdx.x;
  const int w = tid >> 6, lane = tid & 63;
  const int lm = lane & 15, g = lane >> 4;
  const int q8 = g * 8;

  const float* base = qkv + (size_t)b * T_ * 3 * E_;

  // Q B-fragments, prescaled by 1/sqrt(Dh) = 0.125, split hi/lo.
  // B-frag layout (matches working GEMM): n = lane&15, k = (lane>>4)*8 + e (+32*ks)
  short8 qbh[2], qbl[2];
  {
    const int t = qt0 + w * 16 + lm;
    const float* qrow = base + (size_t)t * 3 * E_ + hh * Dh_;
#pragma unroll
    for (int ks = 0; ks < 2; ++ks) {
      float4 f0 = *(const float4*)(qrow + ks * 32 + q8);
      float4 f1 = *(const float4*)(qrow + ks * 32 + q8 + 4);
      float qv[8] = {f0.x, f0.y, f0.z, f0.w, f1.x, f1.y, f1.z, f1.w};
#pragma unroll
      for (int e = 0; e < 8; ++e) {
        float sv = qv[e] * 0.125f;
        unsigned short hv = f2bf(sv);
        qbh[ks][e] = (short)hv;
        qbl[ks][e] = (short)f2bf(sv - bf2f(hv));
      }
    }
  }

  f32x4 o[4];
#pragma unroll
  for (int i = 0; i < 4; ++i) o[i] = {0.f, 0.f, 0.f, 0.f};
  float m_run = -1e30f, l_run = 0.f;

  const int r = tid >> 2, c16 = (tid & 3) * 16;

  for (int s0 = 0; s0 < T_; s0 += 64) {
    // ---- stage K row-major [key][d] + V transposed [d][key], split bf16 ----
    const float* krow = base + (size_t)(s0 + r) * 3 * E_ + E_ + hh * Dh_ + c16;
    const float* vrow = krow + E_;
#pragma unroll
    for (int hf = 0; hf < 2; ++hf) {
      float4 a0 = *(const float4*)(krow + hf * 8);
      float4 a1 = *(const float4*)(krow + hf * 8 + 4);
      float fa[8] = {a0.x, a0.y, a0.z, a0.w, a1.x, a1.y, a1.z, a1.w};
      unsigned short hs[8], ls[8];
#pragma unroll
      for (int j = 0; j < 8; ++j) {
        hs[j] = f2bf(fa[j]);
        ls[j] = f2bf(fa[j] - bf2f(hs[j]));
      }
      uint4 uh, ul;
      uh.x = hs[0] | ((unsigned)hs[1] << 16); uh.y = hs[2] | ((unsigned)hs[3] << 16);
      uh.z = hs[4] | ((unsigned)hs[5] << 16); uh.w = hs[6] | ((unsigned)hs[7] << 16);
      ul.x = ls[0] | ((unsigned)ls[1] << 16); ul.y = ls[2] | ((unsigned)ls[3] << 16);
      ul.z = ls[4] | ((unsigned)ls[5] << 16); ul.w = ls[6] | ((unsigned)ls[7] << 16);
      *(uint4*)&Kh_s[r][c16 + hf * 8] = uh;
      *(uint4*)&Kl_s[r][c16 + hf * 8] = ul;

      float4 c0 = *(const float4*)(vrow + hf * 8);
      float4 c1 = *(const float4*)(vrow + hf * 8 + 4);
      float fc[8] = {c0.x, c0.y, c0.z, c0.w, c1.x, c1.y, c1.z, c1.w};
#pragma unroll
      for (int j = 0; j < 8; ++j) {
        unsigned short hv = f2bf(fc[j]);
        Vth_s[c16 + hf * 8 + j][r] = hv;
        Vtl_s[c16 + hf * 8 + j][r] = f2bf(fc[j] - bf2f(hv));
      }
    }
    __syncthreads();

    // ---- S^T[key][q] = K·Q^T (3-term split-bf16) ----
    f32x4 sf[4];
#pragma unroll
    for (int i = 0; i < 4; ++i) sf[i] = {0.f, 0.f, 0.f, 0.f};
#pragma unroll
    for (int ks = 0; ks < 2; ++ks) {
#pragma unroll
      for (int i = 0; i < 4; ++i) {
        short8 khf = *(const short8*)&Kh_s[i * 16 + lm][ks * 32 + q8];
        short8 klf = *(const short8*)&Kl_s[i * 16 + lm][ks * 32 + q8];
        sf[i] = __builtin_amdgcn_mfma_f32_16x16x32_bf16(khf, qbh[ks], sf[i], 0, 0, 0);
        sf[i] = __builtin_amdgcn_mfma_f32_16x16x32_bf16(klf, qbh[ks], sf[i], 0, 0, 0);
        sf[i] = __builtin_amdgcn_mfma_f32_16x16x32_bf16(khf, qbl[ks], sf[i], 0, 0, 0);
      }
    }

    // ---- online softmax over this tile's 64 keys (per q = lm, in-lane) ----
    // C-layout: col = q = lane&15; row = key = i*16 + (lane>>4)*4 + reg.
    float tmax = -1e30f;
#pragma unroll
    for (int i = 0; i < 4; ++i)
#pragma unroll
      for (int rg = 0; rg < 4; ++rg) tmax = fmaxf(tmax, sf[i][rg]);
    tmax = fmaxf(tmax, __shfl_xor(tmax, 16, 64));
    tmax = fmaxf(tmax, __shfl_xor(tmax, 32, 64));
    float mnew = fmaxf(m_run, tmax);
    float alpha = __expf(m_run - mnew);
    float psum = 0.f;
#pragma unroll
    for (int i = 0; i < 4; ++i)
#pragma unroll
      for (int rg = 0; rg < 4; ++rg) {
        float p = __expf(sf[i][rg] - mnew);
        sf[i][rg] = p;
        psum += p;
      }
    psum += __shfl_xor(psum, 16, 64);
    psum += __shfl_xor(psum, 32, 64);
    l_run = l_run * alpha + psum;
    m_run = mnew;
#pragma unroll
    for (int i = 0; i < 4; ++i) o[i] *= alpha;

    // ---- P -> LDS (hi/lo) in [q][key] layout (keys consecutive in reg -> b64) ----
#pragma unroll
    for (int i = 0; i < 4; ++i) {
      ushort4 ph, pl;
      float p0 = sf[i][0], p1 = sf[i][1], p2 = sf[i][2], p3 = sf[i][3];
      ph.x = f2bf(p0); pl.x = f2bf(p0 - bf2f(ph.x));
      ph.y = f2bf(p1); pl.y = f2bf(p1 - bf2f(ph.y));
      ph.z = f2bf(p2); pl.z = f2bf(p2 - bf2f(ph.z));
      ph.w = f2bf(p3); pl.w = f2bf(p3 - bf2f(ph.w));
      *(ushort4*)&Ph_s[w][lm][i * 16 + g * 4] = ph;
      *(ushort4*)&Pl_s[w][lm][i * 16 + g * 4] = pl;
    }
    // wave-internal LDS write->read ordering (cross-lane), then pin scheduling
    asm volatile("s_waitcnt lgkmcnt(0)" ::: "memory");
    __builtin_amdgcn_sched_barrier(0);

    // ---- O^T[d][q] += V^T · P^T (3-term split-bf16) ----
#pragma unroll
    for (int ks = 0; ks < 2; ++ks) {
      short8 pbh = *(const short8*)&Ph_s[w][lm][ks * 32 + q8];
      short8 pbl = *(const short8*)&Pl_s[w][lm][ks * 32 + q8];
#pragma unroll
      for (int i = 0; i < 4; ++i) {
        short8 vhf = *(const short8*)&Vth_s[i * 16 + lm][ks * 32 + q8];
        short8 vlf = *(const short8*)&Vtl_s[i * 16 + lm][ks * 32 + q8];
        o[i] = __builtin_amdgcn_mfma_f32_16x16x32_bf16(vhf, pbh, o[i], 0, 0, 0);
        o[i] = __builtin_amdgcn_mfma_f32_16x16x32_bf16(vlf, pbh, o[i], 0, 0, 0);
        o[i] = __builtin_amdgcn_mfma_f32_16x16x32_bf16(vhf, pbl, o[i], 0, 0, 0);
      }
    }
    __syncthreads();
  }

  // ---- epilogue: O^T[d][q], d = i*16 + g*4 + reg (consecutive -> float4),
  // q = lm. Written in the SAME tiled att layout the previous kernel used. ----
  const float inv = 1.f / l_run;
  const int t = qt0 + w * 16 + lm;
  float* orow = att + ((size_t)b * T_ + hh * 128 + (t >> 3)) * E_ + (t & 7) * Dh_;
#pragma unroll
  for (int i = 0; i < 4; ++i) {
    f32x4 ov = o[i] * inv;
    *(f32x4*)(orow + i * 16 + g * 4) = ov;
  }
}

// ---------------- router ----------------
__global__ __launch_bounds__(64)
void router_kernel(const float* __restrict__ h,
                   const float* __restrict__ rw, const float* __restrict__ rb,
                   const float* __restrict__ nw, const float* __restrict__ nb,
                   const float* __restrict__ noise,
                   int* __restrict__ topi, float* __restrict__ topg) {
  int tok = blockIdx.x;
  int lane = threadIdx.x;
  const float* hr = h + (size_t)tok * E_;
  __shared__ float lg[X_], nl[X_];
  for (int xj = 0; xj < X_; ++xj) {
    float a = 0.f, c = 0.f;
    for (int dd = lane; dd < E_; dd += 64) {
      float hv = hr[dd];
      a += hv * rw[xj * E_ + dd];
      c += hv * nw[xj * E_ + dd];
    }
    a = wave_sum(a);
    c = wave_sum(c);
    if (lane == 0) { lg[xj] = a + rb[xj]; nl[xj] = c + nb[xj]; }
  }
  __syncthreads();
  if (lane == 0) {
    float noisy[X_];
#pragma unroll
    for (int xj = 0; xj < X_; ++xj) {
      float nv = nl[xj];
      float sp = fmaxf(nv, 0.f) + log1pf(expf(-fabsf(nv)));
      noisy[xj] = lg[xj] + noise[(size_t)tok * X_ + xj] * sp;
    }
    int i0 = 0;
#pragma unroll
    for (int xj = 1; xj < X_; ++xj) if (noisy[xj] > noisy[i0]) i0 = xj;
    int i1 = -1;
#pragma unroll
    for (int xj = 0; xj < X_; ++xj) {
      if (xj == i0) continue;
      if (i1 < 0 || noisy[xj] > noisy[i1]) i1 = xj;
    }
    float e = __expf(noisy[i1] - noisy[i0]);
    float p0 = 1.f / (1.f + e);
    topi[tok * 2] = i0;
    topi[tok * 2 + 1] = i1;
    topg[tok * 2] = p0;
    topg[tok * 2 + 1] = e * p0;
  }
}

// ---------------- per-expert ordered compaction ----------------
__global__ __launch_bounds__(256)
void build_lists_kernel(const int* __restrict__ topi, const float* __restrict__ topg,
                        int* __restrict__ elist, float* __restrict__ eg) {
  int ex = blockIdx.x;
  int tid = threadIdx.x;
  constexpr int PER = NTOK / 256;
  int base = tid * PER;
  int cnt = 0;
  for (int i = 0; i < PER; ++i) {
    int t = base + i;
    if (topi[2 * t] == ex || topi[2 * t + 1] == ex) cnt++;
  }
  __shared__ int s[256];
  s[tid] = cnt;
  __syncthreads();
  for (int off = 1; off < 256; off <<= 1) {
    int v = (tid >= off) ? s[tid - off] : 0;
    __syncthreads();
    s[tid] += v;
    __syncthreads();
  }
  int rank = s[tid] - cnt;
  int total = s[255];
  for (int i = 0; i < PER; ++i) {
    int t = base + i;
    int k0 = topi[2 * t], k1 = topi[2 * t + 1];
    if (k0 == ex || k1 == ex) {
      if (rank < CAP_) {
        elist[ex * CAP_ + rank] = t;
        eg[ex * CAP_ + rank] = (k0 == ex) ? topg[2 * t] : topg[2 * t + 1];
      }
      rank++;
    }
  }
  for (int i = total + tid; i < CAP_; i += 256) {
    elist[ex * CAP_ + i] = 0;
    eg[ex * CAP_ + i] = 0.f;
  }
}

// ---------------- pooling ----------------
__global__ __launch_bounds__(64)
void pool_score_kernel(const float* __restrict__ h, const float* __restrict__ q,
                       float* __restrict__ s) {
  int tok = blockIdx.x;
  int lane = threadIdx.x;
  const float* hr = h + (size_t)tok * E_;
  float a = 0.f;
  for (int dd = lane; dd < E_; dd += 64) a += hr[dd] * q[dd];
  a = wave_sum(a);
  if (lane == 0) s[tok] = a * (1.f / sqrtf((float)E_));
}

__global__ __launch_bounds__(256)
void pool_softmax_kernel(const float* __restrict__ s, float* __restrict__ w) {
  int b = blockIdx.x, tid = threadIdx.x;
  const float* sr = s + (size_t)b * T_;
  float v[4];
  float mx = -1e30f;
#pragma unroll
  for (int i = 0; i < 4; ++i) { v[i] = sr[tid + 256 * i]; mx = fmaxf(mx, v[i]); }
  __shared__ float red[4];
  mx = wave_max(mx);
  if ((tid & 63) == 0) red[tid >> 6] = mx;
  __syncthreads();
  mx = fmaxf(fmaxf(red[0], red[1]), fmaxf(red[2], red[3]));
  float e[4], sum = 0.f;
#pragma unroll
  for (int i = 0; i < 4; ++i) { e[i] = __expf(v[i] - mx); sum += e[i]; }
  sum = wave_sum(sum);
  __syncthreads();
  if ((tid & 63) == 0) red[tid >> 6] = sum;
  __syncthreads();
  float inv = 1.f / (red[0] + red[1] + red[2] + red[3]);
#pragma unroll
  for (int i = 0; i < 4; ++i) w[(size_t)b * T_ + tid + 256 * i] = e[i] * inv;
}

__global__ __launch_bounds__(512)
void pool_weighted_kernel(const float* __restrict__ w, const float* __restrict__ h,
                          float* __restrict__ pooled) {
  int b = blockIdx.x, e = threadIdx.x;
  float acc = 0.f;
  for (int t = 0; t < T_; ++t) acc += w[(size_t)b * T_ + t] * h[((size_t)b * T_ + t) * E_ + e];
  pooled[(size_t)b * E_ + e] = acc;
}

// ---------------- skinny GEMM #1 (direct): C[8][N] = A[8][512] @ W[N][512]^T + bias ----------------
__global__ __launch_bounds__(256)
void skinny_direct_kernel(const float* __restrict__ A, const float* __restrict__ W,
                          const float* __restrict__ bias, float* __restrict__ C, int N) {
  __shared__ float As[8 * 512];
  int tid = threadIdx.x;
  for (int i = tid; i < 8 * 512; i += 256) As[i] = A[i];
  __syncthreads();
  int wid = tid >> 6, lane = tid & 63;
  int n = blockIdx.x * 4 + wid;
  float acc[8] = {};
  const float* Wr = W + (size_t)n * 512;
#pragma unroll
  for (int it = 0; it < 2; ++it) {
    int k = it * 256 + lane * 4;
    float4 wv = *(const float4*)(Wr + k);
#pragma unroll
    for (int b = 0; b < 8; ++b) {
      float4 av = *(const float4*)(As + b * 512 + k);
      acc[b] += av.x * wv.x + av.y * wv.y + av.z * wv.z + av.w * wv.w;
    }
  }
#pragma unroll
  for (int b = 0; b < 8; ++b) {
    float s = wave_sum(acc[b]);
    if (lane == 0) C[(size_t)b * N + n] = s + bias[n];
  }
}

// ---------------- h1 init: h1[b][n] = head_b1[n] ----------------
__global__ __launch_bounds__(256)
void init_h1_kernel(const float* __restrict__ b1, float* __restrict__ h1) {
  int idx = blockIdx.x * 256 + threadIdx.x;
  if (idx < 8 * HID_) h1[idx] = b1[idx & (HID_ - 1)];
}

// ---------------- skinny GEMM #2 (K-split atomic): h1[8][1024] += hv[8][32000] @ W[1024][32000]^T ----------------
__global__ __launch_bounds__(256)
void skinny_split_kernel(const float* __restrict__ A, const float* __restrict__ W,
                         float* __restrict__ C) {
  int tid = threadIdx.x;
  int wid = tid >> 6, lane = tid & 63;
  int n = blockIdx.x * 4 + wid;
  int kbase = blockIdx.y * 1280;
  const float* Wr = W + (size_t)n * HIGH_ + kbase;
  float acc[8] = {};
#pragma unroll
  for (int it = 0; it < 5; ++it) {
    int k = it * 256 + lane * 4;
    float4 wv = *(const float4*)(Wr + k);
#pragma unroll
    for (int b = 0; b < 8; ++b) {
      float4 av = *(const float4*)(A + (size_t)b * HIGH_ + kbase + k);
      acc[b] += av.x * wv.x + av.y * wv.y + av.z * wv.z + av.w * wv.w;
    }
  }
#pragma unroll
  for (int b = 0; b < 8; ++b) {
    float s = wave_sum(acc[b]);
    if (lane == 0) atomicAdd(&C[(size_t)b * HID_ + n], s);
  }
}

// ---------------- head2 with fused relu ----------------
__global__ __launch_bounds__(256)
void head2_kernel(const float* __restrict__ h1, const float* __restrict__ w2,
                  const float* __restrict__ b2, float* __restrict__ out) {
  int b = blockIdx.x, tid = threadIdx.x;
  float a = 0.f;
  for (int j = tid; j < HID_; j += 256) a += fmaxf(h1[(size_t)b * HID_ + j], 0.f) * w2[j];
  a = wave_sum(a);
  __shared__ float red[4];
  if ((tid & 63) == 0) red[tid >> 6] = a;
  __syncthreads();
  if (tid == 0) out[b] = red[0] + red[1] + red[2] + red[3] + b2[0];
}

// ---------------- host launcher ----------------
extern "C" void kernel_launch(void* const* d_in, const int* in_sizes, int n_in,
                              void* d_out, int out_size, void* d_ws, size_t ws_size,
                              hipStream_t stream) {
  const float* tok_emb = (const float*)d_in[0];
  const float* pos_emb = (const float*)d_in[1];
  const float* ln1_w = (const float*)d_in[2];
  const float* ln1_b = (const float*)d_in[3];
  const float* ln2_w = (const float*)d_in[4];
  const float* ln2_b = (const float*)d_in[5];
  const float* qkv_w = (const float*)d_in[6];
  const float* out_w = (const float*)d_in[7];
  const float* route_w = (const float*)d_in[8];
  const float* route_b = (const float*)d_in[9];
  const float* noise_w = (const float*)d_in[10];
  const float* noise_b = (const float*)d_in[11];
  const float* exp_w1 = (const float*)d_in[12];
  const float* exp_b1 = (const float*)d_in[13];
  const float* exp_w2 = (const float*)d_in[14];
  const float* exp_b2 = (const float*)d_in[15];
  const float* lnf_w = (const float*)d_in[16];
  const float* lnf_b = (const float*)d_in[17];
  const float* pool_q = (const float*)d_in[18];
  const float* pool_w = (const float*)d_in[19];
  const float* pool_b = (const float*)d_in[20];
  const float* head_w1 = (const float*)d_in[21];
  const float* head_b1 = (const float*)d_in[22];
  const float* head_w2 = (const float*)d_in[23];
  const float* head_b2 = (const float*)d_in[24];
  const int* ids = (const int*)d_in[25];
  const float* rnoise = (const float*)d_in[26];
  float* out = (float*)d_out;
  (void)in_sizes; (void)n_in; (void)out_size;

  constexpr size_t XE = (size_t)NTOK * E_;          // 4.19M
  constexpr size_t W1EL = (size_t)FF_ * E_;         // 1.05M
  constexpr size_t W2EL = (size_t)E_ * FF_;         // 1.05M
  constexpr size_t HIDEL = (size_t)CAP_ * FF_;      // 4.19M

  char* base = (char*)d_ws;
  size_t cur = 0;
  auto alloc_f = [&](size_t nel) { float* p = (float*)(base + cur); cur += nel * 4; return p; };
  auto alloc_u = [&](size_t nel) { unsigned short* p = (unsigned short*)(base + cur); cur += nel * 2; return p; };

  float* x = alloc_f(XE);
  float* h = alloc_f(XE);           // also holds att
  float* qkv = alloc_f((size_t)NTOK * 3 * E_);
  float* sbuf = alloc_f(NTOK);
  float* wbuf = alloc_f(NTOK);
  float* pooled = alloc_f(B_ * E_);
  float* hv = alloc_f((size_t)B_ * HIGH_);
  float* h1 = alloc_f(B_ * HID_);
  float* topg = alloc_f(NTOK * 2);
  float* eg = alloc_f(X_ * CAP_);
  int* topi = (int*)alloc_f(NTOK * 2);
  int* elist = (int*)alloc_f(X_ * CAP_);
  unsigned short* h2h = alloc_u(XE);   // also att2 hi
  unsigned short* h2l = alloc_u(XE);   // also att2 lo
  unsigned short* qwh = alloc_u((size_t)3 * E_ * E_);
  unsigned short* qwl = alloc_u((size_t)3 * E_ * E_);
  unsigned short* owh = alloc_u((size_t)E_ * E_);
  unsigned short* owl = alloc_u((size_t)E_ * E_);

  // expert-phase buffers: prefer tail of ws; else overlay the (dead) qkv region
  size_t perexp_bytes = 2ull * 2ull * (W1EL + W2EL + HIDEL);  // hi+lo, 2B each
  size_t tail_avail = (ws_size > cur) ? (ws_size - cur) : 0;
  int NB = (int)(tail_avail / perexp_bytes);
  unsigned short* earea;
  if (NB >= 1) {
    earea = (unsigned short*)(base + cur);
    if (NB > X_) NB = X_;
  } else {
    NB = 1;
    earea = (unsigned short*)qkv;  // 50.3 MB region >= 25.2 MB needed
  }
  unsigned short* w1h = earea;
  unsigned short* w1l = w1h + (size_t)NB * W1EL;
  unsigned short* w2h = w1l + (size_t)NB * W1EL;
  unsigned short* w2l = w2h + (size_t)NB * W2EL;
  unsigned short* hidh = w2l + (size_t)NB * W2EL;
  unsigned short* hidl = hidh + (size_t)NB * HIDEL;

  auto cast_grid = [](size_t n) { return dim3((unsigned)((n / 4 + 255) / 256)); };

  embed_kernel<<<NTOK, 256, 0, stream>>>(tok_emb, pos_emb, ids, x);

  for (int l = 0; l < L_; ++l) {
    ln_kernel<<<NTOK, 256, 0, stream>>>(x, ln1_w + l * E_, ln1_b + l * E_, h);
    split_cast_kernel<<<cast_grid(XE), 256, 0, stream>>>(h, h2h, h2l, (int)XE);
    split_cast_kernel<<<cast_grid(3 * E_ * E_), 256, 0, stream>>>(
        qkv_w + (size_t)l * 3 * E_ * E_, qwh, qwl, 3 * E_ * E_);
    mfma_gemm<0><<<dim3(12, 64), 256, 0, stream>>>(h2h, h2l, E_, qwh, qwl, nullptr, qkv,
                                                   nullptr, nullptr, nullptr, nullptr, 0,
                                                   NTOK, 3 * E_, E_);
    rope_kernel<<<NTOK, 256, 0, stream>>>(qkv);
    {
      dim3 g(T_ / 64, B_ * Hn_);
      attn_mfma_kernel<<<g, 256, 0, stream>>>(qkv, h);  // att -> h
    }
    split_cast_kernel<<<cast_grid(XE), 256, 0, stream>>>(h, h2h, h2l, (int)XE);  // att2
    split_cast_kernel<<<cast_grid(E_ * E_), 256, 0, stream>>>(
        out_w + (size_t)l * E_ * E_, owh, owl, E_ * E_);
    mfma_gemm<1><<<dim3(4, 64), 256, 0, stream>>>(h2h, h2l, E_, owh, owl, nullptr, x,
                                                  nullptr, nullptr, nullptr, nullptr, 0,
                                                  NTOK, E_, E_);
    ln_kernel<<<NTOK, 256, 0, stream>>>(x, ln2_w + l * E_, ln2_b + l * E_, h);
    split_cast_kernel<<<cast_grid(XE), 256, 0, stream>>>(h, h2h, h2l, (int)XE);
    router_kernel<<<NTOK, 64, 0, stream>>>(h, route_w + (size_t)l * X_ * E_, route_b + l * X_,
                                           noise_w + (size_t)l * X_ * E_, noise_b + l * X_,
                                           rnoise + (size_t)l * NTOK * X_, topi, topg);
    build_lists_kernel<<<X_, 256, 0, stream>>>(topi, topg, elist, eg);

    for (int e0 = 0; e0 < X_; e0 += NB) {
      int nb = (X_ - e0 < NB) ? (X_ - e0) : NB;
      split_cast_kernel<<<cast_grid((size_t)nb * W1EL), 256, 0, stream>>>(
          exp_w1 + ((size_t)l * X_ + e0) * W1EL, w1h, w1l, (int)(nb * W1EL));
      split_cast_kernel<<<cast_grid((size_t)nb * W2EL), 256, 0, stream>>>(
          exp_w2 + ((size_t)l * X_ + e0) * W2EL, w2h, w2l, (int)(nb * W2EL));
      mfma_gemm<2><<<dim3(FF_ / 128, CAP_ / 128, nb), 256, 0, stream>>>(
          h2h, h2l, E_, w1h, w1l, exp_b1 + (size_t)l * X_ * FF_, nullptr,
          hidh, hidl, elist, nullptr, e0, CAP_, FF_, E_);
      mfma_gemm<3><<<dim3(E_ / 128, CAP_ / 128, nb), 256, 0, stream>>>(
          hidh, hidl, FF_, w2h, w2l, exp_b2 + (size_t)l * X_ * E_, x,
          nullptr, nullptr, elist, eg, e0, CAP_, E_, FF_);
    }
  }

  ln_kernel<<<NTOK, 256, 0, stream>>>(x, lnf_w, lnf_b, h);
  pool_score_kernel<<<NTOK, 64, 0, stream>>>(h, pool_q, sbuf);
  pool_softmax_kernel<<<B_, 256, 0, stream>>>(sbuf, wbuf);
  pool_weighted_kernel<<<B_, 512, 0, stream>>>(wbuf, h, pooled);
  skinny_direct_kernel<<<HIGH_ / 4, 256, 0, stream>>>(pooled, pool_w, pool_b, hv, HIGH_);
  init_h1_kernel<<<(8 * HID_ + 255) / 256, 256, 0, stream>>>(head_b1, h1);
  {
    dim3 g(HID_ / 4, 25);
    skinny_split_kernel<<<g, 256, 0, stream>>>(hv, head_w1, h1);
  }
  head2_kernel<<<B_, 256, 0, stream>>>(h1, head_w2, head_b2, out);
}